// Round 15
// baseline (105.106 us; speedup 1.0000x reference)
//
#include <hip/hip_runtime.h>
#include <hip/hip_bf16.h>

typedef __bf16 bf16;
typedef __attribute__((ext_vector_type(4))) __bf16 bf16x4;
typedef __attribute__((ext_vector_type(8))) __bf16 bf16x8;
typedef __attribute__((ext_vector_type(4))) float f32x4;

#define SEQ   4096
#define DIMN  1024
#define NHEAD 8
#define HD    128
#define MALL  4160   /* 4096 X rows + 64 Cp rows */
#define PENV  -10000.0f
#define NKT   32     /* K-steps of 32 */
#define NCVT  4160   /* blocks for cvt part of prep */

typedef const __attribute__((address_space(1))) void gvoid_t;
typedef __attribute__((address_space(3))) void lvoid_t;

// ---------------------------------------------------------------- prep: fused {fp32->bf16 X++Cp} + {W transpose}
__global__ __launch_bounds__(256) void prep_kernel(
    const float* __restrict__ X, const float* __restrict__ Cp,
    const float* __restrict__ W0, const float* __restrict__ W1, const float* __restrict__ W2,
    bf16* __restrict__ A, bf16* __restrict__ Wt) {
  const int bid = blockIdx.x;
  if (bid < NCVT) {
    size_t base = ((size_t)bid * 256 + threadIdx.x) * 4;
    const float* src = (base < (size_t)SEQ * DIMN) ? (X + base) : (Cp + (base - (size_t)SEQ * DIMN));
    float4 v = *(const float4*)src;
    bf16x4 o;
    o[0] = (bf16)v.x; o[1] = (bf16)v.y; o[2] = (bf16)v.z; o[3] = (bf16)v.w;
    *(bf16x4*)&A[base] = o;
  } else {
    int tid2 = bid - NCVT;
    int z = tid2 >> 8, rem = tid2 & 255;
    int by = rem >> 4, bx = rem & 15;
    const float* W = (z == 0) ? W0 : ((z == 1) ? W1 : W2);
    bf16* dst = Wt + (size_t)z * DIMN * DIMN;
    __shared__ bf16 tile[64][72];
    int k0 = by * 64, n0 = bx * 64;
    int tx = threadIdx.x & 63, ty = threadIdx.x >> 6;
#pragma unroll
    for (int r = ty; r < 64; r += 4)
      tile[tx][r] = (bf16)W[(size_t)(k0 + r) * DIMN + n0 + tx];
    __syncthreads();
#pragma unroll
    for (int r = ty; r < 64; r += 4)
      dst[(size_t)(n0 + r) * DIMN + k0 + tx] = tile[r][tx];
  }
}

// ---------------------------------------------------------------- fused QKV GEMM — co-residency geometry (R15).
// 256x128 tile, BK=32, 4 waves (2m x 2n; per-wave 128x64 = SAME density/acc as R6), dbuf-2
// = 48KB LDS -> up to 3 blocks/CU; 400 blocks -> >=2 co-resident blocks hide barrier/vmcnt
// convoys (the R6-class grid was 204 blocks on 256 CUs = 1/CU, stalls fully exposed).
// XOR swizzle for BK=32: cc ^= (row>>1)&3 on BOTH source and read sides (2-way max).
// Coalesced epilogues (R13/R14) re-fit as quarter passes in 48KB.
// z = 0:Q [m][n], 1:K [m][n], 2:V stored TRANSPOSED VT[n][m].
__global__ __launch_bounds__(256) void gemm_qkv_kernel(
    const bf16* __restrict__ A, const bf16* __restrict__ Wt,
    const float* __restrict__ bQ, const float* __restrict__ bK, const float* __restrict__ bV,
    bf16* __restrict__ QKV) {
  const int z = blockIdx.z;
  const int M = (z == 0) ? SEQ : MALL;
  const int m0 = blockIdx.y * 256;
  if (m0 >= M) return;
  const int n0 = blockIdx.x * 128;
  const bf16* Wz = Wt + (size_t)z * DIMN * DIMN;
  const float* bias = (z == 0) ? bQ : ((z == 1) ? bK : bV);
  bf16* out = QKV + (size_t)z * MALL * DIMN;

  __shared__ bf16 SMEM[24576];   // 48KB: Ab[2] @0/8192 (256x32 each), Bb[2] @16384/20480 (128x32)

  const int t = threadIdx.x;
  const int lane = t & 63, w = t >> 6;
  const int wm = w >> 1, wn = w & 1;          // 2m x 2n waves; per-wave output 128x64
  const int r16 = lane & 15, g4 = lane >> 4;

  f32x4 acc[8][4] = {};

  // Stage A panel (256x32, 16KB = 4 gloads/thread) of step k into Ab[k&1].
  auto stageA = [&](int k) {
    bf16* dst = SMEM + (k & 1) * 8192;
#pragma unroll
    for (int i = 0; i < 4; ++i) {
      int segBase = (i * 4 + w) * 64;
      int seg = segBase + lane;
      int row = seg >> 2;
      int cc = (seg & 3) ^ ((row >> 1) & 3);   // source-side swizzle (BK=32)
      int gm = m0 + row; gm = (gm < M) ? gm : (M - 1);
      __builtin_amdgcn_global_load_lds(
          (gvoid_t*)(A + (size_t)gm * DIMN + k * 32 + cc * 8),
          (lvoid_t*)(dst + segBase * 8), 16, 0, 0);
    }
  };
  // Stage B panel (128x32, 8KB = 2 gloads/thread) into Bb[k&1].
  auto stageB = [&](int k) {
    bf16* dst = SMEM + 16384 + (k & 1) * 4096;
#pragma unroll
    for (int i = 0; i < 2; ++i) {
      int segBase = (i * 4 + w) * 64;
      int seg = segBase + lane;
      int row = seg >> 2;
      int cc = (seg & 3) ^ ((row >> 1) & 3);
      int gn = n0 + row;                       // always < 1024
      __builtin_amdgcn_global_load_lds(
          (gvoid_t*)(Wz + (size_t)gn * DIMN + k * 32 + cc * 8),
          (lvoid_t*)(dst + segBase * 8), 16, 0, 0);
    }
  };

  auto rdA = [&](const bf16* Ax, int mf) -> bf16x8 {
    int row = wm * 128 + mf * 16 + r16;
    return *(const bf16x8*)&Ax[row * 32 + ((g4 ^ ((row >> 1) & 3)) * 8)];
  };
  auto rdB = [&](const bf16* Bx, int nf) -> bf16x8 {
    int row = wn * 64 + nf * 16 + r16;
    return *(const bf16x8*)&Bx[row * 32 + ((g4 ^ ((row >> 1) & 3)) * 8)];
  };

  stageA(0); stageB(0);
  asm volatile("s_waitcnt vmcnt(0)" ::: "memory");
  __builtin_amdgcn_s_barrier();

  for (int k = 0; k < NKT; ++k) {
    const bf16* Ax = SMEM + (k & 1) * 8192;
    const bf16* Bx = SMEM + 16384 + (k & 1) * 4096;
    bf16x8 aL[4], aH[4], bF[4];

    // Sub-phase 1: lo A-frags + B-frags, stage next A, 16 MFMA.
#pragma unroll
    for (int mf = 0; mf < 4; ++mf) aL[mf] = rdA(Ax, mf);
#pragma unroll
    for (int nf = 0; nf < 4; ++nf) bF[nf] = rdB(Bx, nf);
    if (k + 1 < NKT) stageA(k + 1);
    __builtin_amdgcn_sched_barrier(0);
    __builtin_amdgcn_s_setprio(1);
#pragma unroll
    for (int mf = 0; mf < 4; ++mf)
#pragma unroll
      for (int nf = 0; nf < 4; ++nf)
        acc[mf][nf] = __builtin_amdgcn_mfma_f32_16x16x32_bf16(aL[mf], bF[nf], acc[mf][nf], 0, 0, 0);
    __builtin_amdgcn_s_setprio(0);

    // Sub-phase 2: hi A-frags (bF reused from registers), stage next B, 16 MFMA.
#pragma unroll
    for (int mf = 0; mf < 4; ++mf) aH[mf] = rdA(Ax, 4 + mf);
    if (k + 1 < NKT) stageB(k + 1);
    __builtin_amdgcn_sched_barrier(0);
    __builtin_amdgcn_s_setprio(1);
#pragma unroll
    for (int mf = 0; mf < 4; ++mf)
#pragma unroll
      for (int nf = 0; nf < 4; ++nf)
        acc[4 + mf][nf] = __builtin_amdgcn_mfma_f32_16x16x32_bf16(aH[mf], bF[nf], acc[4 + mf][nf], 0, 0, 0);
    __builtin_amdgcn_s_setprio(0);

    if (k + 1 < NKT) {
      asm volatile("s_waitcnt vmcnt(0)" ::: "memory");  // next step's 6 stages landed
      __builtin_amdgcn_s_barrier();                     // + all waves done reading this buf
    }
  }

  // ---- epilogue: LDS-coalesced, quarter passes (48KB budget). acc[mf][nf] maps to
  //      m = m0 + wm*128 + mf*16 + g4*4 + r ; n = n0 + wn*64 + nf*16 + r16.
  __syncthreads();   // K-loop fully drained before SMEM reuse
  if (z == 2) {
    // VT[n][m]: per m-quarter q (64 m): T[n_loc][66], writers wm==q>>1, mf in (q&1)*4+0..3.
    bf16* T = SMEM;   // 128 x 66 x 2B = 16.9KB
#pragma unroll
    for (int q = 0; q < 4; ++q) {
      if ((m0 + q * 64) < M) {
        if (wm == (q >> 1)) {
#pragma unroll
          for (int nf = 0; nf < 4; ++nf) {
            int n_loc = wn * 64 + nf * 16 + r16;
            float bv = bias[n0 + n_loc];
#pragma unroll
            for (int mfq = 0; mfq < 4; ++mfq) {
              int mf = (q & 1) * 4 + mfq;
              bf16x4 o;
#pragma unroll
              for (int r = 0; r < 4; ++r) o[r] = (bf16)(acc[mf][nf][r] + bv);
              *(bf16x4*)&T[n_loc * 66 + mfq * 16 + g4 * 4] = o;
            }
          }
        }
        __syncthreads();
#pragma unroll
        for (int it = 0; it < 4; ++it) {
          int idx = it * 256 + t;
          int n_loc = idx >> 3, m8 = (idx & 7) * 8;
          bf16x8 v = *(const bf16x8*)&T[n_loc * 66 + m8];
          *(bf16x8*)&out[(size_t)(n0 + n_loc) * MALL + m0 + q * 64 + m8] = v;
        }
        __syncthreads();
      }
    }
  } else {
    // Q/K row-major: per m-quarter q: T[m_in_q][264]; 16 lanes write a 256B run along n.
    bf16* T = SMEM;   // 64 x 264 x 2B = 33.8KB
#pragma unroll
    for (int q = 0; q < 4; ++q) {
      if ((m0 + q * 64) < M) {
        if (wm == (q >> 1)) {
#pragma unroll
          for (int nf = 0; nf < 4; ++nf) {
            int n_loc = wn * 64 + nf * 16 + r16;
            float bv = bias[n0 + n_loc];
#pragma unroll
            for (int mfq = 0; mfq < 4; ++mfq) {
              int mf = (q & 1) * 4 + mfq;
              int mb = mfq * 16 + g4 * 4;
#pragma unroll
              for (int r = 0; r < 4; ++r)
                T[(mb + r) * 264 + n_loc] = (bf16)(acc[mf][nf][r] + bv);
            }
          }
        }
        __syncthreads();
#pragma unroll
        for (int it = 0; it < 4; ++it) {
          int idx = it * 256 + t;
          int m_rel = idx >> 4, n8 = (idx & 15) * 8;
          int gm = m0 + q * 64 + m_rel;
          if (gm < M) {
            bf16x8 v = *(const bf16x8*)&T[m_rel * 264 + n8];
            *(bf16x8*)&out[(size_t)gm * DIMN + n0 + n8] = v;
          }
        }
        __syncthreads();
      }
    }
  }
}

// ---------------------------------------------------------------- key slot -> global row map (band paths)
__device__ __forceinline__ int key_row_map(int qb, int tslot) {
  if (qb <= 1) return tslot;                                    // rows 0..255
  if (qb == 63) return (tslot < 64) ? tslot : (3840 + tslot);   // block0 then blocks 61..63
  return (tslot < 64) ? tslot : ((qb - 1) * 64 + (tslot - 64)); // block0 + 3-block window
}

// ---------------------------------------------------------------- fused attention — R12 (unchanged)
__global__ __launch_bounds__(256) void attn_kernel(
    const bf16* __restrict__ Q, const bf16* __restrict__ K, const bf16* __restrict__ VT,
    const float* __restrict__ mask, float* __restrict__ out) {
  const int bid = blockIdx.x;
  const int h = bid & 7, qb = bid >> 3;
  const int t = threadIdx.x;
  const int lane = t & 63, w = t >> 6;
  const int c16 = lane & 15, g4 = lane >> 4;
  const float sl = exp2f(-(float)(h + 1));
  const float rsq = 0.088388347648318447f;  // 1/sqrt(128)

  __shared__ bf16 KB[2][8192];   // 16 KiB ring buffers (K tile or V^T slab), swizzled contents
  __shared__ bf16 P[64][328];    // band P cols 0..255, packed P cols 256..319 (+8 pad)

  bf16x8 qf[4];
  {
    int srow = qb * 64 + w * 16 + c16;
    const bf16* qp = Q + (size_t)srow * DIMN + h * HD + g4 * 8;
#pragma unroll
    for (int ks = 0; ks < 4; ++ks) qf[ks] = *(const bf16x8*)(qp + ks * 32);
  }
  int iq[4]; float mi[4];
#pragma unroll
  for (int r = 0; r < 4; ++r) { iq[r] = qb * 64 + w * 16 + g4 * 4 + r; mi[r] = mask[iq[r]]; }
  float mjv[16];
#pragma unroll
  for (int f = 0; f < 16; ++f) mjv[f] = mask[key_row_map(qb, f * 16 + c16)];
  __builtin_amdgcn_sched_barrier(0);

  const bf16* vt_h = VT + (size_t)h * HD * MALL;

  auto stageC = [&](int c) {
    int b = c & 1;
    if (c < 5) {
#pragma unroll
      for (int i = 0; i < 4; ++i) {
        int segBase = i * 256 + w * 64;
        int seg = segBase + lane;
        int kr = seg >> 4;
        int cc = (seg & 15) ^ (kr & 7);   // source-side swizzle
        int gr = (c == 4) ? (SEQ + kr) : key_row_map(qb, c * 64 + kr);
        __builtin_amdgcn_global_load_lds(
            (gvoid_t*)(K + (size_t)gr * DIMN + h * HD + cc * 8),
            (lvoid_t*)(&KB[b][segBase * 8]), 16, 0, 0);
      }
    } else {
      int j = c - 5;
      int colbase = (j == 4) ? SEQ : key_row_map(qb, j * 64);  // 64 contiguous rows in all cases
#pragma unroll
      for (int i = 0; i < 4; ++i) {
        int segBase = i * 256 + w * 64;
        int seg = segBase + lane;
        int dr = seg >> 3;
        int cc = (seg & 7) ^ (dr & 7);
        __builtin_amdgcn_global_load_lds(
            (gvoid_t*)(vt_h + (size_t)dr * MALL + colbase + cc * 8),
            (lvoid_t*)(&KB[b][segBase * 8]), 16, 0, 0);
      }
    }
  };

  f32x4 sc[16] = {};
  f32x4 sp[4] = {};

  auto biasChunk = [&](int c) {
#pragma unroll
    for (int kj = 0; kj < 4; ++kj) {
      int f = c * 4 + kj;
      int tslot = f * 16 + c16;
      int jrow = key_row_map(qb, tslot);
      float mj = mjv[f];
      int jpos = (qb == 63) ? (3840 + tslot) : jrow;   // last block: virtual key positions
      int ishift = (qb >= 2 && qb <= 62) ? 128 : 0;    // middle band: row-counter-from-0 quirk
#pragma unroll
      for (int r = 0; r < 4; ++r) {
        float raw = sc[f][r];
        float dist = sl * fabsf((float)(iq[r] - ishift - jpos));
        float s;
        if (qb <= 1)       s = raw * rsq - dist + (1.f - mi[r]) * PENV;
        else if (qb == 63) s = raw * rsq - dist;
        else {
          float pen = (tslot < 64) ? (1.f - mi[r]) * PENV : (1.f - mi[r] * mj) * PENV;
          s = (raw + pen) * rsq - dist;
        }
        sc[f][r] = s;
      }
    }
  };

  // ---- QK^T over 5 K-chunks, distance-1 prefetch, counted vmcnt, bias(c-1) as VALU filler.
  stageC(0);
#pragma unroll
  for (int c = 0; c < 5; ++c) {
    stageC(c + 1);                                     // c=4 stages V0 -> covered by softmax
    if (c >= 1) biasChunk(c - 1);                      // chunks 0..3 biased exactly once
    asm volatile("s_waitcnt vmcnt(4)" ::: "memory");   // chunk c resident; c+1 flies
    __builtin_amdgcn_s_barrier();
    const bf16* Kx = &KB[c & 1][0];
    __builtin_amdgcn_s_setprio(1);
#pragma unroll
    for (int ks = 0; ks < 4; ++ks)
#pragma unroll
      for (int kj = 0; kj < 4; ++kj) {
        int row = kj * 16 + c16;
        bf16x8 bfr = *(const bf16x8*)&Kx[row * 128 + (((ks * 4 + g4) ^ (row & 7)) * 8)];
        if (c < 4)
          sc[c * 4 + kj] = __builtin_amdgcn_mfma_f32_16x16x32_bf16(qf[ks], bfr, sc[c * 4 + kj], 0, 0, 0);
        else
          sp[kj] = __builtin_amdgcn_mfma_f32_16x16x32_bf16(qf[ks], bfr, sp[kj], 0, 0, 0);
      }
    __builtin_amdgcn_s_setprio(0);
    __builtin_amdgcn_s_barrier();   // all waves done reading KB[c&1] before restage
  }

  // ---- band softmax (256 keys) -> P cols 0..255 (wave-private rows)
#pragma unroll
  for (int r = 0; r < 4; ++r) {
    float m = -1e30f;
#pragma unroll
    for (int f = 0; f < 16; ++f) m = fmaxf(m, sc[f][r]);
#pragma unroll
    for (int d = 1; d < 16; d <<= 1) m = fmaxf(m, __shfl_xor(m, d));
    float s = 0.f;
#pragma unroll
    for (int f = 0; f < 16; ++f) { float e = __expf(sc[f][r] - m); sc[f][r] = e; s += e; }
#pragma unroll
    for (int d = 1; d < 16; d <<= 1) s += __shfl_xor(s, d);
    float inv = 1.0f / s;
#pragma unroll
    for (int f = 0; f < 16; ++f)
      P[w * 16 + g4 * 4 + r][f * 16 + c16] = (bf16)(sc[f][r] * inv);
  }
  // ---- packed softmax (64 keys; constants cancel) -> P cols 256..319
#pragma unroll
  for (int r = 0; r < 4; ++r) {
    float m = -1e30f;
#pragma unroll
    for (int kj = 0; kj < 4; ++kj) m = fmaxf(m, sp[kj][r] * rsq);
#pragma unroll
    for (int d = 1; d < 16; d <<= 1) m = fmaxf(m, __shfl_xor(m, d));
    float s = 0.f;
    float e[4];
#pragma unroll
    for (int kj = 0; kj < 4; ++kj) { e[kj] = __expf(sp[kj][r] * rsq - m); s += e[kj]; }
#pragma unroll
    for (int d = 1; d < 16; d <<= 1) s += __shfl_xor(s, d);
    float inv = mi[r] / s;  // packed context pre-scaled by mask_v
#pragma unroll
    for (int kj = 0; kj < 4; ++kj)
      P[w * 16 + g4 * 4 + r][256 + kj * 16 + c16] = (bf16)(e[kj] * inv);
  }

  // ---- PV over 5 V-chunks through the same ring.
  f32x4 ctx[8] = {};
#pragma unroll
  for (int j = 0; j < 5; ++j) {
    int c = j + 5;
    if (c < 9) {
      stageC(c + 1);
      asm volatile("s_waitcnt vmcnt(4)" ::: "memory");
    } else {
      asm volatile("s_waitcnt vmcnt(0)" ::: "memory");
    }
    __builtin_amdgcn_s_barrier();
    const bf16* Vx = &KB[c & 1][0];
    int pcol = (j < 4) ? j * 64 : 256;
    __builtin_amdgcn_s_setprio(1);
#pragma unroll
    for (int ks = 0; ks < 2; ++ks) {
      bf16x8 pa = *(const bf16x8*)&P[w * 16 + c16][pcol + ks * 32 + g4 * 8];
#pragma unroll
      for (int df = 0; df < 8; ++df) {
        int row = df * 16 + c16;
        bf16x8 bv = *(const bf16x8*)&Vx[row * 64 + (((ks * 4 + g4) ^ (row & 7)) * 8)];
        ctx[df] = __builtin_amdgcn_mfma_f32_16x16x32_bf16(pa, bv, ctx[df], 0, 0, 0);
      }
    }
    __builtin_amdgcn_s_setprio(0);
    __builtin_amdgcn_s_barrier();
  }

  // ---- output: raw [H,S,hd] flatten; final mask uses reshaped-row quirk mask[h*512 + s/8]
#pragma unroll
  for (int df = 0; df < 8; ++df) {
    int d = df * 16 + c16;
#pragma unroll
    for (int r = 0; r < 4; ++r) {
      int s = iq[r];
      float fm = mask[h * 512 + (s >> 3)];
      out[(size_t)h * (SEQ * HD) + (size_t)s * HD + d] = ctx[df][r] * fm;
    }
  }
}

// ---------------------------------------------------------------- launch
extern "C" void kernel_launch(void* const* d_in, const int* in_sizes, int n_in,
                              void* d_out, int out_size, void* d_ws, size_t ws_size,
                              hipStream_t stream) {
  const float* X    = (const float*)d_in[0];
  const float* Cp   = (const float*)d_in[1];
  const float* mask = (const float*)d_in[2];
  const float* WQ   = (const float*)d_in[3];
  const float* bQ   = (const float*)d_in[4];
  const float* WK   = (const float*)d_in[5];
  const float* bK   = (const float*)d_in[6];
  const float* WV   = (const float*)d_in[7];
  const float* bV   = (const float*)d_in[8];
  float* out = (float*)d_out;

  bf16* Abf = (bf16*)d_ws;                              // [4160][1024]
  bf16* Wt  = Abf + (size_t)MALL * DIMN;                // 3 x [1024][1024] (transposed)
  bf16* QKV = Wt + (size_t)3 * DIMN * DIMN;             // q[4160][1024], k[4160][1024], VT[1024][4160]

  prep_kernel<<<NCVT + 768, 256, 0, stream>>>(X, Cp, WQ, WK, WV, Abf, Wt);
  gemm_qkv_kernel<<<dim3(8, 17, 3), 256, 0, stream>>>(Abf, Wt, bQ, bK, bV, QKV);
  attn_kernel<<<512, 256, 0, stream>>>(QKV, QKV + (size_t)MALL * DIMN,
                                       QKV + (size_t)2 * MALL * DIMN, mask, out);
}

// Round 16
// 62.501 us; speedup vs baseline: 1.6817x; 1.6817x over previous
//
#include <hip/hip_runtime.h>
#include <hip/hip_bf16.h>

typedef __bf16 bf16;
typedef __attribute__((ext_vector_type(4))) __bf16 bf16x4;
typedef __attribute__((ext_vector_type(8))) __bf16 bf16x8;
typedef __attribute__((ext_vector_type(4))) float f32x4;

#define SEQ   4096
#define DIMN  1024
#define NHEAD 8
#define HD    128
#define MALL  4160   /* 4096 X rows + 64 Cp rows */
#define PENV  -10000.0f
#define NT    16     /* K-tiles of 64 */
#define NCVT  4160   /* blocks for cvt part of prep */
#define GWG   204    /* gemm blocks: 3 z x 17 my x 4 nx */

typedef const __attribute__((address_space(1))) void gvoid_t;
typedef __attribute__((address_space(3))) void lvoid_t;

// ---------------------------------------------------------------- prep: fused {fp32->bf16 X++Cp} + {W transpose}
__global__ __launch_bounds__(256) void prep_kernel(
    const float* __restrict__ X, const float* __restrict__ Cp,
    const float* __restrict__ W0, const float* __restrict__ W1, const float* __restrict__ W2,
    bf16* __restrict__ A, bf16* __restrict__ Wt) {
  const int bid = blockIdx.x;
  if (bid < NCVT) {
    size_t base = ((size_t)bid * 256 + threadIdx.x) * 4;
    const float* src = (base < (size_t)SEQ * DIMN) ? (X + base) : (Cp + (base - (size_t)SEQ * DIMN));
    float4 v = *(const float4*)src;
    bf16x4 o;
    o[0] = (bf16)v.x; o[1] = (bf16)v.y; o[2] = (bf16)v.z; o[3] = (bf16)v.w;
    *(bf16x4*)&A[base] = o;
  } else {
    int tid2 = bid - NCVT;
    int z = tid2 >> 8, rem = tid2 & 255;
    int by = rem >> 4, bx = rem & 15;
    const float* W = (z == 0) ? W0 : ((z == 1) ? W1 : W2);
    bf16* dst = Wt + (size_t)z * DIMN * DIMN;
    __shared__ bf16 tile[64][72];
    int k0 = by * 64, n0 = bx * 64;
    int tx = threadIdx.x & 63, ty = threadIdx.x >> 6;
#pragma unroll
    for (int r = ty; r < 64; r += 4)
      tile[tx][r] = (bf16)W[(size_t)(k0 + r) * DIMN + n0 + tx];
    __syncthreads();
#pragma unroll
    for (int r = ty; r < 64; r += 4)
      dst[(size_t)(n0 + r) * DIMN + k0 + tx] = tile[r][tx];
  }
}

// ---------------------------------------------------------------- fused QKV GEMM — R14 structure (best measured)
// + bijective XCD-chunked blockIdx remap (T1/m204): the 4 n-sibling tiles of one (z,m) land on
// ONE XCD -> shared A/B panels become L2 hits instead of cross-XCD L3 refetches.
// 256^2 tile, BK=64, dbuf-2, XOR chunk swizzle, 4 sub-phases/tile; coalesced LDS epilogues.
// z = 0:Q [m][n], 1:K [m][n], 2:V stored TRANSPOSED VT[n][m].
__global__ __launch_bounds__(512) void gemm_qkv_kernel(
    const bf16* __restrict__ A, const bf16* __restrict__ Wt,
    const float* __restrict__ bQ, const float* __restrict__ bK, const float* __restrict__ bV,
    bf16* __restrict__ QKV) {
  // Bijective XCD-chunk remap: orig%8 = XCD (dispatch round-robin); give each XCD a
  // CONTIGUOUS range of logical tiles. nwg=204: q=25, r=4 (XCD 0-3 get 26, XCD 4-7 get 25).
  const int orig = blockIdx.x;
  const int xcd = orig & 7, slot = orig >> 3;
  const int wgid = (xcd < 4 ? xcd * 26 : 104 + (xcd - 4) * 25) + slot;
  const int z = wgid / 68;
  const int rem = wgid % 68;
  const int m0 = (rem >> 2) * 256;
  const int n0 = (rem & 3) * 256;
  const int M = (z == 0) ? SEQ : MALL;
  if (m0 >= M) return;
  const bf16* Wz = Wt + (size_t)z * DIMN * DIMN;
  const float* bias = (z == 0) ? bQ : ((z == 1) ? bK : bV);
  bf16* out = QKV + (size_t)z * MALL * DIMN;

  __shared__ bf16 SMEM[4][256 * 64];   // 128 KiB; [0..1]=Ab dbuf, [2..3]=Bb dbuf; reused as T in epilogue
  bf16 (*Ab)[256 * 64] = &SMEM[0];
  bf16 (*Bb)[256 * 64] = &SMEM[2];

  const int t = threadIdx.x;
  const int lane = t & 63, w = t >> 6;
  const int wm = w >> 2, wn = w & 3;
  const int r16 = lane & 15, g4 = lane >> 4;

  f32x4 acc[8][4] = {};

  auto stageA = [&](int k) {
    int b = k & 1;
#pragma unroll
    for (int i = 0; i < 4; ++i) {
      int segBase = i * 512 + w * 64;
      int seg = segBase + lane;
      int row = seg >> 3;
      int cc = (seg & 7) ^ (row & 7);
      int gm = m0 + row; gm = (gm < M) ? gm : (M - 1);
      __builtin_amdgcn_global_load_lds(
          (gvoid_t*)(A + (size_t)gm * DIMN + k * 64 + cc * 8),
          (lvoid_t*)(&Ab[b][segBase * 8]), 16, 0, 0);
    }
  };
  auto stageB = [&](int k) {
    int b = k & 1;
#pragma unroll
    for (int i = 0; i < 4; ++i) {
      int segBase = i * 512 + w * 64;
      int seg = segBase + lane;
      int row = seg >> 3;
      int cc = (seg & 7) ^ (row & 7);
      int gn = n0 + row;
      __builtin_amdgcn_global_load_lds(
          (gvoid_t*)(Wz + (size_t)gn * DIMN + k * 64 + cc * 8),
          (lvoid_t*)(&Bb[b][segBase * 8]), 16, 0, 0);
    }
  };

  auto rdA = [&](const bf16* Ax, int mf, int kk) -> bf16x8 {
    int row = wm * 128 + mf * 16 + r16;
    return *(const bf16x8*)&Ax[row * 64 + (((kk * 4 + g4) ^ (row & 7)) * 8)];
  };
  auto rdB = [&](const bf16* Bx, int nf, int kk) -> bf16x8 {
    int row = wn * 64 + nf * 16 + r16;
    return *(const bf16x8*)&Bx[row * 64 + (((kk * 4 + g4) ^ (row & 7)) * 8)];
  };

  stageA(0); stageB(0);
  asm volatile("s_waitcnt vmcnt(0)" ::: "memory");
  __builtin_amdgcn_s_barrier();

  for (int k = 0; k < NT; ++k) {
    const bf16* Ax = &Ab[k & 1][0];
    const bf16* Bx = &Bb[k & 1][0];
    bf16x8 aL[4], aH[4], bL[4];

#pragma unroll
    for (int mf = 0; mf < 4; ++mf) aL[mf] = rdA(Ax, mf, 0);
#pragma unroll
    for (int nf = 0; nf < 4; ++nf) bL[nf] = rdB(Bx, nf, 0);
#pragma unroll
    for (int mf = 0; mf < 4; ++mf) aH[mf] = rdA(Ax, 4 + mf, 0);
    if (k + 1 < NT) stageA(k + 1);
    __builtin_amdgcn_sched_barrier(0);

    __builtin_amdgcn_s_setprio(1);
#pragma unroll
    for (int mf = 0; mf < 4; ++mf)
#pragma unroll
      for (int nf = 0; nf < 4; ++nf)
        acc[mf][nf] = __builtin_amdgcn_mfma_f32_16x16x32_bf16(aL[mf], bL[nf], acc[mf][nf], 0, 0, 0);
    __builtin_amdgcn_s_setprio(0);

    bf16x8 aL2[4], bL2[4];
#pragma unroll
    for (int mf = 0; mf < 4; ++mf) aL2[mf] = rdA(Ax, mf, 1);
#pragma unroll
    for (int nf = 0; nf < 4; ++nf) bL2[nf] = rdB(Bx, nf, 1);
    if (k + 1 < NT) stageB(k + 1);
    __builtin_amdgcn_sched_barrier(0);

    __builtin_amdgcn_s_setprio(1);
#pragma unroll
    for (int mf = 0; mf < 4; ++mf)
#pragma unroll
      for (int nf = 0; nf < 4; ++nf)
        acc[4 + mf][nf] = __builtin_amdgcn_mfma_f32_16x16x32_bf16(aH[mf], bL[nf], acc[4 + mf][nf], 0, 0, 0);
    __builtin_amdgcn_s_setprio(0);

#pragma unroll
    for (int mf = 0; mf < 4; ++mf) aH[mf] = rdA(Ax, 4 + mf, 1);

    __builtin_amdgcn_s_setprio(1);
#pragma unroll
    for (int mf = 0; mf < 4; ++mf)
#pragma unroll
      for (int nf = 0; nf < 4; ++nf)
        acc[mf][nf] = __builtin_amdgcn_mfma_f32_16x16x32_bf16(aL2[mf], bL2[nf], acc[mf][nf], 0, 0, 0);

#pragma unroll
    for (int mf = 0; mf < 4; ++mf)
#pragma unroll
      for (int nf = 0; nf < 4; ++nf)
        acc[4 + mf][nf] = __builtin_amdgcn_mfma_f32_16x16x32_bf16(aH[mf], bL2[nf], acc[4 + mf][nf], 0, 0, 0);
    __builtin_amdgcn_s_setprio(0);

    if (k + 1 < NT) {
      asm volatile("s_waitcnt vmcnt(0)" ::: "memory");
      __builtin_amdgcn_s_barrier();
    }
  }

  // ---- epilogue (all paths LDS-coalesced; R13/R14)
  if (z == 2) {
    bf16* T = &SMEM[0][0];   // 256 x 132 x 2B, two m-half passes
    __syncthreads();
#pragma unroll
    for (int h = 0; h < 2; ++h) {
      if (wm == h) {
#pragma unroll
        for (int nf = 0; nf < 4; ++nf) {
          int n_loc = wn * 64 + nf * 16 + r16;
          float bv = bias[n0 + n_loc];
#pragma unroll
          for (int mf = 0; mf < 8; ++mf) {
            int m_rel = mf * 16 + g4 * 4;
            bf16x4 o;
#pragma unroll
            for (int r = 0; r < 4; ++r) o[r] = (bf16)(acc[mf][nf][r] + bv);
            *(bf16x4*)&T[n_loc * 132 + m_rel] = o;
          }
        }
      }
      __syncthreads();
#pragma unroll
      for (int it = 0; it < 8; ++it) {
        int n_loc = it * 32 + (t >> 4);
        int m8 = (t & 15) * 8;
        int gm = m0 + h * 128 + m8;
        if (gm < M) {
          bf16x8 v = *(const bf16x8*)&T[n_loc * 132 + m8];
          *(bf16x8*)&out[(size_t)(n0 + n_loc) * MALL + gm] = v;
        }
      }
      __syncthreads();
    }
  } else {
    bf16* T = &SMEM[0][0];   // 128 x 264 x 2B, two m-half passes
    __syncthreads();
#pragma unroll
    for (int h = 0; h < 2; ++h) {
      if (wm == h) {
#pragma unroll
        for (int nf = 0; nf < 4; ++nf) {
          int n_loc = wn * 64 + nf * 16 + r16;
          float bv = bias[n0 + n_loc];
#pragma unroll
          for (int mf = 0; mf < 8; ++mf) {
            int mb = mf * 16 + g4 * 4;
#pragma unroll
            for (int r = 0; r < 4; ++r)
              T[(mb + r) * 264 + n_loc] = (bf16)(acc[mf][nf][r] + bv);
          }
        }
      }
      __syncthreads();
#pragma unroll
      for (int it = 0; it < 8; ++it) {
        int m_rel = it * 16 + (t >> 5);
        int n8 = (t & 31) * 8;
        int gm = m0 + h * 128 + m_rel;
        if (gm < M) {
          bf16x8 v = *(const bf16x8*)&T[m_rel * 264 + n8];
          *(bf16x8*)&out[(size_t)gm * DIMN + n0 + n8] = v;
        }
      }
      __syncthreads();
    }
  }
}

// ---------------------------------------------------------------- key slot -> global row map (band paths)
__device__ __forceinline__ int key_row_map(int qb, int tslot) {
  if (qb <= 1) return tslot;                                    // rows 0..255
  if (qb == 63) return (tslot < 64) ? tslot : (3840 + tslot);   // block0 then blocks 61..63
  return (tslot < 64) ? tslot : ((qb - 1) * 64 + (tslot - 64)); // block0 + 3-block window
}

// ---------------------------------------------------------------- fused attention — R12 (unchanged)
__global__ __launch_bounds__(256) void attn_kernel(
    const bf16* __restrict__ Q, const bf16* __restrict__ K, const bf16* __restrict__ VT,
    const float* __restrict__ mask, float* __restrict__ out) {
  const int bid = blockIdx.x;
  const int h = bid & 7, qb = bid >> 3;
  const int t = threadIdx.x;
  const int lane = t & 63, w = t >> 6;
  const int c16 = lane & 15, g4 = lane >> 4;
  const float sl = exp2f(-(float)(h + 1));
  const float rsq = 0.088388347648318447f;  // 1/sqrt(128)

  __shared__ bf16 KB[2][8192];   // 16 KiB ring buffers (K tile or V^T slab), swizzled contents
  __shared__ bf16 P[64][328];    // band P cols 0..255, packed P cols 256..319 (+8 pad)

  bf16x8 qf[4];
  {
    int srow = qb * 64 + w * 16 + c16;
    const bf16* qp = Q + (size_t)srow * DIMN + h * HD + g4 * 8;
#pragma unroll
    for (int ks = 0; ks < 4; ++ks) qf[ks] = *(const bf16x8*)(qp + ks * 32);
  }
  int iq[4]; float mi[4];
#pragma unroll
  for (int r = 0; r < 4; ++r) { iq[r] = qb * 64 + w * 16 + g4 * 4 + r; mi[r] = mask[iq[r]]; }
  float mjv[16];
#pragma unroll
  for (int f = 0; f < 16; ++f) mjv[f] = mask[key_row_map(qb, f * 16 + c16)];
  __builtin_amdgcn_sched_barrier(0);

  const bf16* vt_h = VT + (size_t)h * HD * MALL;

  auto stageC = [&](int c) {
    int b = c & 1;
    if (c < 5) {
#pragma unroll
      for (int i = 0; i < 4; ++i) {
        int segBase = i * 256 + w * 64;
        int seg = segBase + lane;
        int kr = seg >> 4;
        int cc = (seg & 15) ^ (kr & 7);   // source-side swizzle
        int gr = (c == 4) ? (SEQ + kr) : key_row_map(qb, c * 64 + kr);
        __builtin_amdgcn_global_load_lds(
            (gvoid_t*)(K + (size_t)gr * DIMN + h * HD + cc * 8),
            (lvoid_t*)(&KB[b][segBase * 8]), 16, 0, 0);
      }
    } else {
      int j = c - 5;
      int colbase = (j == 4) ? SEQ : key_row_map(qb, j * 64);  // 64 contiguous rows in all cases
#pragma unroll
      for (int i = 0; i < 4; ++i) {
        int segBase = i * 256 + w * 64;
        int seg = segBase + lane;
        int dr = seg >> 3;
        int cc = (seg & 7) ^ (dr & 7);
        __builtin_amdgcn_global_load_lds(
            (gvoid_t*)(vt_h + (size_t)dr * MALL + colbase + cc * 8),
            (lvoid_t*)(&KB[b][segBase * 8]), 16, 0, 0);
      }
    }
  };

  f32x4 sc[16] = {};
  f32x4 sp[4] = {};

  auto biasChunk = [&](int c) {
#pragma unroll
    for (int kj = 0; kj < 4; ++kj) {
      int f = c * 4 + kj;
      int tslot = f * 16 + c16;
      int jrow = key_row_map(qb, tslot);
      float mj = mjv[f];
      int jpos = (qb == 63) ? (3840 + tslot) : jrow;   // last block: virtual key positions
      int ishift = (qb >= 2 && qb <= 62) ? 128 : 0;    // middle band: row-counter-from-0 quirk
#pragma unroll
      for (int r = 0; r < 4; ++r) {
        float raw = sc[f][r];
        float dist = sl * fabsf((float)(iq[r] - ishift - jpos));
        float s;
        if (qb <= 1)       s = raw * rsq - dist + (1.f - mi[r]) * PENV;
        else if (qb == 63) s = raw * rsq - dist;
        else {
          float pen = (tslot < 64) ? (1.f - mi[r]) * PENV : (1.f - mi[r] * mj) * PENV;
          s = (raw + pen) * rsq - dist;
        }
        sc[f][r] = s;
      }
    }
  };

  // ---- QK^T over 5 K-chunks, distance-1 prefetch, counted vmcnt, bias(c-1) as VALU filler.
  stageC(0);
#pragma unroll
  for (int c = 0; c < 5; ++c) {
    stageC(c + 1);                                     // c=4 stages V0 -> covered by softmax
    if (c >= 1) biasChunk(c - 1);                      // chunks 0..3 biased exactly once
    asm volatile("s_waitcnt vmcnt(4)" ::: "memory");   // chunk c resident; c+1 flies
    __builtin_amdgcn_s_barrier();
    const bf16* Kx = &KB[c & 1][0];
    __builtin_amdgcn_s_setprio(1);
#pragma unroll
    for (int ks = 0; ks < 4; ++ks)
#pragma unroll
      for (int kj = 0; kj < 4; ++kj) {
        int row = kj * 16 + c16;
        bf16x8 bfr = *(const bf16x8*)&Kx[row * 128 + (((ks * 4 + g4) ^ (row & 7)) * 8)];
        if (c < 4)
          sc[c * 4 + kj] = __builtin_amdgcn_mfma_f32_16x16x32_bf16(qf[ks], bfr, sc[c * 4 + kj], 0, 0, 0);
        else
          sp[kj] = __builtin_amdgcn_mfma_f32_16x16x32_bf16(qf[ks], bfr, sp[kj], 0, 0, 0);
      }
    __builtin_amdgcn_s_setprio(0);
    __builtin_amdgcn_s_barrier();   // all waves done reading KB[c&1] before restage
  }

  // ---- band softmax (256 keys) -> P cols 0..255 (wave-private rows)
#pragma unroll
  for (int r = 0; r < 4; ++r) {
    float m = -1e30f;
#pragma unroll
    for (int f = 0; f < 16; ++f) m = fmaxf(m, sc[f][r]);
#pragma unroll
    for (int d = 1; d < 16; d <<= 1) m = fmaxf(m, __shfl_xor(m, d));
    float s = 0.f;
#pragma unroll
    for (int f = 0; f < 16; ++f) { float e = __expf(sc[f][r] - m); sc[f][r] = e; s += e; }
#pragma unroll
    for (int d = 1; d < 16; d <<= 1) s += __shfl_xor(s, d);
    float inv = 1.0f / s;
#pragma unroll
    for (int f = 0; f < 16; ++f)
      P[w * 16 + g4 * 4 + r][f * 16 + c16] = (bf16)(sc[f][r] * inv);
  }
  // ---- packed softmax (64 keys; constants cancel) -> P cols 256..319
#pragma unroll
  for (int r = 0; r < 4; ++r) {
    float m = -1e30f;
#pragma unroll
    for (int kj = 0; kj < 4; ++kj) m = fmaxf(m, sp[kj][r] * rsq);
#pragma unroll
    for (int d = 1; d < 16; d <<= 1) m = fmaxf(m, __shfl_xor(m, d));
    float s = 0.f;
    float e[4];
#pragma unroll
    for (int kj = 0; kj < 4; ++kj) { e[kj] = __expf(sp[kj][r] * rsq - m); s += e[kj]; }
#pragma unroll
    for (int d = 1; d < 16; d <<= 1) s += __shfl_xor(s, d);
    float inv = mi[r] / s;  // packed context pre-scaled by mask_v
#pragma unroll
    for (int kj = 0; kj < 4; ++kj)
      P[w * 16 + g4 * 4 + r][256 + kj * 16 + c16] = (bf16)(e[kj] * inv);
  }

  // ---- PV over 5 V-chunks through the same ring.
  f32x4 ctx[8] = {};
#pragma unroll
  for (int j = 0; j < 5; ++j) {
    int c = j + 5;
    if (c < 9) {
      stageC(c + 1);
      asm volatile("s_waitcnt vmcnt(4)" ::: "memory");
    } else {
      asm volatile("s_waitcnt vmcnt(0)" ::: "memory");
    }
    __builtin_amdgcn_s_barrier();
    const bf16* Vx = &KB[c & 1][0];
    int pcol = (j < 4) ? j * 64 : 256;
    __builtin_amdgcn_s_setprio(1);
#pragma unroll
    for (int ks = 0; ks < 2; ++ks) {
      bf16x8 pa = *(const bf16x8*)&P[w * 16 + c16][pcol + ks * 32 + g4 * 8];
#pragma unroll
      for (int df = 0; df < 8; ++df) {
        int row = df * 16 + c16;
        bf16x8 bv = *(const bf16x8*)&Vx[row * 64 + (((ks * 4 + g4) ^ (row & 7)) * 8)];
        ctx[df] = __builtin_amdgcn_mfma_f32_16x16x32_bf16(pa, bv, ctx[df], 0, 0, 0);
      }
    }
    __builtin_amdgcn_s_setprio(0);
    __builtin_amdgcn_s_barrier();
  }

  // ---- output: raw [H,S,hd] flatten; final mask uses reshaped-row quirk mask[h*512 + s/8]
#pragma unroll
  for (int df = 0; df < 8; ++df) {
    int d = df * 16 + c16;
#pragma unroll
    for (int r = 0; r < 4; ++r) {
      int s = iq[r];
      float fm = mask[h * 512 + (s >> 3)];
      out[(size_t)h * (SEQ * HD) + (size_t)s * HD + d] = ctx[df][r] * fm;
    }
  }
}

// ---------------------------------------------------------------- launch
extern "C" void kernel_launch(void* const* d_in, const int* in_sizes, int n_in,
                              void* d_out, int out_size, void* d_ws, size_t ws_size,
                              hipStream_t stream) {
  const float* X    = (const float*)d_in[0];
  const float* Cp   = (const float*)d_in[1];
  const float* mask = (const float*)d_in[2];
  const float* WQ   = (const float*)d_in[3];
  const float* bQ   = (const float*)d_in[4];
  const float* WK   = (const float*)d_in[5];
  const float* bK   = (const float*)d_in[6];
  const float* WV   = (const float*)d_in[7];
  const float* bV   = (const float*)d_in[8];
  float* out = (float*)d_out;

  bf16* Abf = (bf16*)d_ws;                              // [4160][1024]
  bf16* Wt  = Abf + (size_t)MALL * DIMN;                // 3 x [1024][1024] (transposed)
  bf16* QKV = Wt + (size_t)3 * DIMN * DIMN;             // q[4160][1024], k[4160][1024], VT[1024][4160]

  prep_kernel<<<NCVT + 768, 256, 0, stream>>>(X, Cp, WQ, WK, WV, Abf, Wt);
  gemm_qkv_kernel<<<GWG, 512, 0, stream>>>(Abf, Wt, bQ, bK, bV, QKV);
  attn_kernel<<<512, 256, 0, stream>>>(QKV, QKV + (size_t)MALL * DIMN,
                                       QKV + (size_t)2 * MALL * DIMN, mask, out);
}